// Round 1
// baseline (1065.495 us; speedup 1.0000x reference)
//
#include <hip/hip_runtime.h>
#include <hip/hip_bf16.h>

// Sizes (fixed by the reference)
// M=2 branches, K=3 diffusion, N=64, I=1, H=64, B=8, T=12
// Bn = B*N*N = 32768 sequences.

__global__ void k_whhT(const float* __restrict__ whh, float* __restrict__ whhT) {
    // whhT[m][k][g] = whh[m][g][k];  m:2, g:256, k:64
    int idx = blockIdx.x * 256 + threadIdx.x;     // 0..32767
    int m = idx >> 14;
    int r = idx & 16383;
    int k = r >> 8;
    int g = r & 255;
    whhT[idx] = whh[(m * 256 + g) * 64 + k];
}

__global__ __launch_bounds__(256) void k_lstm(
    const float* __restrict__ x, const float* __restrict__ wih,
    const float* __restrict__ whhT, const float* __restrict__ bih,
    const float* __restrict__ bhh, float* __restrict__ hout)
{
    __shared__ float hl[2][64][65];
    const int tid = threadIdx.x;
    const int sq = tid & 63;                                  // sequence-in-block (= d index)
    const int s = __builtin_amdgcn_readfirstlane(tid >> 6);   // wave-uniform H-slice 0..3
    const int br = blockIdx.y;                                // branch
    const int bx = blockIdx.x;                                // 0..511
    const int b = bx >> 6, o = bx & 63;

    // zero h buffer 0
    {
        float* hz = &hl[0][0][0];
        for (int i = tid; i < 64 * 65; i += 256) hz[i] = 0.f;
    }
    __syncthreads();

    float c[16];
#pragma unroll
    for (int j = 0; j < 16; ++j) c[j] = 0.f;

    const float* wihb = wih + br * 256;
    const float* bi = bih + br * 256;
    const float* bh = bhh + br * 256;
    const float* wT = whhT + br * 16384;

    for (int t = 0; t < 12; ++t) {
        const float xv = x[((b * 12 + t) * 64 + o) * 64 + sq];
        float acc[4][16];
#pragma unroll
        for (int gg = 0; gg < 4; ++gg) {
            const int row0 = gg * 64 + s * 16;
#pragma unroll
            for (int j = 0; j < 16; ++j) {
                float bsum = bi[row0 + j] + bh[row0 + j];
                acc[gg][j] = fmaf(xv, wihb[row0 + j], bsum);
            }
        }
        const float* hrow = &hl[t & 1][0][0];
#pragma unroll 2
        for (int k = 0; k < 64; ++k) {
            const float hv = hrow[sq * 65 + k];
            const float* wr = wT + k * 256 + s * 16;
#pragma unroll
            for (int gg = 0; gg < 4; ++gg) {
#pragma unroll
                for (int j = 0; j < 16; ++j)
                    acc[gg][j] = fmaf(hv, wr[gg * 64 + j], acc[gg][j]);
            }
        }
        // activations: i,f,g,o
        float* hw = &hl[(t & 1) ^ 1][0][0];
#pragma unroll
        for (int j = 0; j < 16; ++j) {
            float is = 1.f / (1.f + __expf(-acc[0][j]));
            float fs = 1.f / (1.f + __expf(-acc[1][j]));
            float e2 = __expf(2.f * acc[2][j]);
            float gt = (e2 - 1.f) / (e2 + 1.f);
            float os = 1.f / (1.f + __expf(-acc[3][j]));
            c[j] = fs * c[j] + is * gt;
            float e2c = __expf(2.f * c[j]);
            float tc = (e2c - 1.f) / (e2c + 1.f);
            hw[sq * 65 + s * 16 + j] = os * tc;
        }
        __syncthreads();
    }
    // final h is in buffer 0 (t=11 wrote (11&1)^1 = 0). Transposed, coalesced store.
    const int k2 = tid & 63;
#pragma unroll
    for (int j = 0; j < 16; ++j) {
        int sq2 = s * 16 + j;
        hout[(size_t)(br * 8 + b) * 262144 + (size_t)o * 4096 + sq2 * 64 + k2] =
            hl[0][sq2][k2];
    }
}

// T1[o][b][mm][c][l] = sum_n G[br][o][n][mm] * Xin[br,b][n][c][l]
__global__ __launch_bounds__(256) void k_t1(
    const float* __restrict__ Xin, const float* __restrict__ G,
    float* __restrict__ T1, int br)
{
    const int o = blockIdx.y >> 3, b = blockIdx.y & 7;
    const int cl = blockIdx.x * 256 + threadIdx.x;            // 0..4095 (c*64+l)
    const float* xp = Xin + (size_t)(br * 8 + b) * 262144 + cl;
    const float* gp = G + (size_t)((br * 3 + o) * 64) * 64;   // [n][mm]
    float acc[64];
#pragma unroll
    for (int mm = 0; mm < 64; ++mm) acc[mm] = 0.f;
#pragma unroll 4
    for (int n = 0; n < 64; ++n) {
        float xv = xp[(size_t)n * 4096];
        const float* gr = gp + n * 64;
#pragma unroll
        for (int mm = 0; mm < 64; ++mm) acc[mm] = fmaf(xv, gr[mm], acc[mm]);
    }
    float* tp = T1 + (size_t)((o * 8 + b) * 64) * 4096 + cl;
#pragma unroll
    for (int mm = 0; mm < 64; ++mm) tp[(size_t)mm * 4096] = acc[mm];
}

// Per (br, b, mm): out[e][h] = sum_{o,d,l} W[(o*3+d)*64+l][h] * Z_od[e][l],
//   Z_od[e][l] = sum_c G[br][d][c][e] * T1[o][b][mm][c][l]
__global__ __launch_bounds__(256) void k_t2fc(
    const float* __restrict__ T1, const float* __restrict__ G,
    const float* __restrict__ W, const float* __restrict__ bias,
    float* __restrict__ Y, int br)
{
    __shared__ float t1s[3 * 64 * 64];
    __shared__ float zl[64 * 65];
    const int mm = blockIdx.x, b = blockIdx.y;
    const int lane = threadIdx.x & 63;
    const int q = __builtin_amdgcn_readfirstlane(threadIdx.x >> 6);  // 0..3

    for (int i = threadIdx.x; i < 3 * 4096; i += 256)
        t1s[i] = T1[(size_t)(((i >> 12) * 8 + b) * 64 + mm) * 4096 + (i & 4095)];
    __syncthreads();

    float out[16];
#pragma unroll
    for (int j = 0; j < 16; ++j) out[j] = 0.f;

    const float* gb = G + (size_t)(br * 3) * 4096;
    const float* wb = W + (size_t)br * 576 * 64;

    for (int o = 0; o < 3; ++o) {
        for (int d = 0; d < 3; ++d) {
            // Z phase: thread handles column l=lane, e in [q*16, q*16+16)
            float z[16];
#pragma unroll
            for (int j = 0; j < 16; ++j) z[j] = 0.f;
            const float* t1c = t1s + o * 4096 + lane;
            const float* gd = gb + d * 4096 + q * 16;
#pragma unroll 2
            for (int cc = 0; cc < 64; ++cc) {
                float tv = t1c[cc * 64];
                const float* gr = gd + cc * 64;
#pragma unroll
                for (int j = 0; j < 16; ++j) z[j] = fmaf(tv, gr[j], z[j]);
            }
#pragma unroll
            for (int j = 0; j < 16; ++j) zl[(q * 16 + j) * 65 + lane] = z[j];
            __syncthreads();
            // FC phase: thread handles e=lane, h in [q*16, q*16+16)
            const float* wr = wb + (size_t)((o * 3 + d) * 64) * 64 + q * 16;
            const float* zr = zl + lane * 65;
#pragma unroll 2
            for (int l = 0; l < 64; ++l) {
                float zv = zr[l];
                const float* w4 = wr + l * 64;
#pragma unroll
                for (int j = 0; j < 16; ++j) out[j] = fmaf(zv, w4[j], out[j]);
            }
            __syncthreads();
        }
    }
    // transpose via LDS, add bias, coalesced store
#pragma unroll
    for (int j = 0; j < 16; ++j) zl[lane * 65 + q * 16 + j] = out[j];
    __syncthreads();
    const float bv = bias[br * 64 + lane];
    float* yp = Y + (size_t)(br * 8 + b) * 262144 + (size_t)mm * 4096 + lane;
#pragma unroll
    for (int j = 0; j < 16; ++j) {
        int e = q * 16 + j;
        yp[(size_t)e * 64] = zl[e * 65 + lane] + bv;
    }
}

__global__ __launch_bounds__(256) void k_fc(
    const float* __restrict__ Y2, const float* __restrict__ fcW,
    const float* __restrict__ fcb, float* __restrict__ out)
{
    int idx = blockIdx.x * 256 + threadIdx.x;  // 0..32767 = b*4096 + n*64 + d
    int b = idx >> 12, nd = idx & 4095;
    float r = 0.f;
#pragma unroll
    for (int br = 0; br < 2; ++br) {
        const float4* yp =
            (const float4*)(Y2 + (size_t)(br * 8 + b) * 262144 + (size_t)nd * 64);
        float acc = 0.f;
#pragma unroll
        for (int v = 0; v < 16; ++v) {
            float4 y4 = yp[v];
            const float* fw = fcW + br * 64 + v * 4;
            acc += y4.x * fw[0] + y4.y * fw[1] + y4.z * fw[2] + y4.w * fw[3];
        }
        acc += fcb[br];
        r += fmaxf(acc, 0.f);
    }
    out[idx] = 0.5f * r;
}

extern "C" void kernel_launch(void* const* d_in, const int* in_sizes, int n_in,
                              void* d_out, int out_size, void* d_ws, size_t ws_size,
                              hipStream_t stream)
{
    const float* x   = (const float*)d_in[0];
    const float* G   = (const float*)d_in[1];
    const float* wih = (const float*)d_in[2];
    const float* whh = (const float*)d_in[3];
    const float* bih = (const float*)d_in[4];
    const float* bhh = (const float*)d_in[5];
    const float* W0  = (const float*)d_in[6];
    const float* b0  = (const float*)d_in[7];
    const float* W1  = (const float*)d_in[8];
    const float* b1  = (const float*)d_in[9];
    const float* fcW = (const float*)d_in[10];
    const float* fcb = (const float*)d_in[11];
    float* out = (float*)d_out;

    float* ws   = (float*)d_ws;
    float* whhT = ws;                       // 32768 floats
    float* X0   = ws + 32768;               // 4,194,304 floats (LSTM h / layer1 in)
    float* T1b  = X0 + 4194304;             // 6,291,456 floats (per-branch T1)
    float* Y1   = T1b + 6291456;            // 4,194,304 floats (layer1 out)
    float* Y2   = X0;                       // reuse: layer2 out

    k_whhT<<<128, 256, 0, stream>>>(whh, whhT);
    k_lstm<<<dim3(512, 2), 256, 0, stream>>>(x, wih, whhT, bih, bhh, X0);

    for (int br = 0; br < 2; ++br) {
        k_t1<<<dim3(16, 24), 256, 0, stream>>>(X0, G, T1b, br);
        k_t2fc<<<dim3(64, 8), 256, 0, stream>>>(T1b, G, W0, b0, Y1, br);
    }
    for (int br = 0; br < 2; ++br) {
        k_t1<<<dim3(16, 24), 256, 0, stream>>>(Y1, G, T1b, br);
        k_t2fc<<<dim3(64, 8), 256, 0, stream>>>(T1b, G, W1, b1, Y2, br);
    }
    k_fc<<<128, 256, 0, stream>>>(Y2, fcW, fcb, out);
}

// Round 2
// 748.848 us; speedup vs baseline: 1.4228x; 1.4228x over previous
//
#include <hip/hip_runtime.h>
#include <hip/hip_bf16.h>

// M=2 branches, K=3 diffusion, N=64, I=1, H=64, B=8, T=12

typedef __attribute__((ext_vector_type(8))) short short8;   // 8 bf16 (4 VGPRs)
typedef __attribute__((ext_vector_type(4))) float f32x4;    // 4 fp32

__device__ __forceinline__ short bf16_hi_trunc(float f) {
    union { float f; unsigned u; } v; v.f = f;
    return (short)(v.u >> 16);
}
__device__ __forceinline__ float trunc_bf16_f32(float f) {
    union { float f; unsigned u; } v; v.f = f;
    v.u &= 0xFFFF0000u;
    return v.f;
}
__device__ __forceinline__ short bf16_rne(float f) {
    union { float f; unsigned u; } v; v.f = f;
    unsigned r = ((v.u >> 16) & 1u) + 0x7FFFu;
    return (short)((v.u + r) >> 16);
}
__device__ __forceinline__ float sigmoidf_(float x) {
    return 1.f / (1.f + __expf(-x));
}
__device__ __forceinline__ float tanhf_(float x) {
    float e = __expf(-2.f * x);               // tanh = 2/(1+e^-2x) - 1, no inf/inf
    return fmaf(2.f, 1.f / (1.f + e), -1.f);
}

// LSTM via bf16x3-split MFMA. Block = (br, b, o): 64 sequences, 4 waves.
// gates[64 seq][256] = h[64][64] @ WhhT[64][256]; wave w owns gate cols
// {gg*64 + w*16 .. +15} for gg=0..3 (one 16-col slice of each gate type).
__global__ __launch_bounds__(256, 2) void k_lstm(
    const float* __restrict__ x, const float* __restrict__ whh,
    const float* __restrict__ wih, const float* __restrict__ bih,
    const float* __restrict__ bhh, float* __restrict__ hout)
{
    __shared__ short hbuf[2][2][64][64];  // [dbuf][hi/lo][seq][hid ^ swz]
    const int tid = threadIdx.x;
    const int lane = tid & 63;
    const int w = __builtin_amdgcn_readfirstlane(tid >> 6);
    const int q = lane >> 4;          // 0..3 (k-group / seq-subrow)
    const int r16 = lane & 15;
    const int br = blockIdx.y;
    const int b = blockIdx.x >> 6, o = blockIdx.x & 63;

    // Weight-stationary B fragments, hi/lo bf16 split (16 frags = 64 VGPR).
    // B[k][gate]: gate = lane&15 (+tile), k = (lane>>4)*8 + j.
    short8 Bhi[2][4], Blo[2][4];
    float wihv[4], biasv[4];
#pragma unroll
    for (int gg = 0; gg < 4; ++gg) {
        const int gate = gg * 64 + w * 16 + r16;
        wihv[gg] = wih[br * 256 + gate];
        biasv[gg] = bih[br * 256 + gate] + bhh[br * 256 + gate];
#pragma unroll
        for (int kt = 0; kt < 2; ++kt) {
            const float* wp = whh + ((size_t)br * 256 + gate) * 64 + kt * 32 + q * 8;
            float4 f0 = *(const float4*)wp;
            float4 f1 = *(const float4*)(wp + 4);
            float fv[8] = {f0.x, f0.y, f0.z, f0.w, f1.x, f1.y, f1.z, f1.w};
            short8 hi8, lo8;
#pragma unroll
            for (int j = 0; j < 8; ++j) {
                hi8[j] = bf16_hi_trunc(fv[j]);
                lo8[j] = bf16_rne(fv[j] - trunc_bf16_f32(fv[j]));
            }
            Bhi[kt][gg] = hi8;
            Blo[kt][gg] = lo8;
        }
    }

    float cst[4][4];
#pragma unroll
    for (int mt = 0; mt < 4; ++mt)
#pragma unroll
        for (int r = 0; r < 4; ++r) cst[mt][r] = 0.f;

    const float* xb = x + (((size_t)b * 12) * 64 + o) * 64;
    float* hob = hout + (size_t)(br * 8 + b) * 262144 + (size_t)o * 4096;

    for (int t = 0; t < 12; ++t) {
        // acc init: x*wih + bias. D layout: col=lane&15, row=(lane>>4)*4+r.
        f32x4 acc[4][4];   // [mt][gg]
        const float* xrow = xb + (size_t)t * 4096;
#pragma unroll
        for (int mt = 0; mt < 4; ++mt) {
#pragma unroll
            for (int r = 0; r < 4; ++r) {
                float xv = xrow[mt * 16 + q * 4 + r];
#pragma unroll
                for (int gg = 0; gg < 4; ++gg)
                    acc[mt][gg][r] = fmaf(xv, wihv[gg], biasv[gg]);
            }
        }
        if (t > 0) {
            const short* hb = &hbuf[t & 1][0][0][0];
#pragma unroll
            for (int kt = 0; kt < 2; ++kt) {
                short8 Ahi[4], Alo[4];
#pragma unroll
                for (int mt = 0; mt < 4; ++mt) {
                    // A[row][k]: row = mt*16 + (lane&15), k = kt*32 + q*8 + j
                    int elem = (mt * 16 + r16) * 64 +
                               ((kt * 32 + q * 8) ^ ((r16 & 7) << 3));
                    Ahi[mt] = *(const short8*)(hb + elem);
                    Alo[mt] = *(const short8*)(hb + 4096 + elem);
                }
#pragma unroll
                for (int mt = 0; mt < 4; ++mt)
#pragma unroll
                    for (int gg = 0; gg < 4; ++gg) {
                        acc[mt][gg] = __builtin_amdgcn_mfma_f32_16x16x32_bf16(
                            Ahi[mt], Bhi[kt][gg], acc[mt][gg], 0, 0, 0);
                        acc[mt][gg] = __builtin_amdgcn_mfma_f32_16x16x32_bf16(
                            Ahi[mt], Blo[kt][gg], acc[mt][gg], 0, 0, 0);
                        acc[mt][gg] = __builtin_amdgcn_mfma_f32_16x16x32_bf16(
                            Alo[mt], Bhi[kt][gg], acc[mt][gg], 0, 0, 0);
                    }
            }
        }
        // activations (torch gate order i,f,g,o), write h hi/lo to LDS
        short* hwH = &hbuf[(t + 1) & 1][0][0][0];
        const int hid = w * 16 + r16;
#pragma unroll
        for (int mt = 0; mt < 4; ++mt) {
#pragma unroll
            for (int r = 0; r < 4; ++r) {
                float ig = sigmoidf_(acc[mt][0][r]);
                float fg = sigmoidf_(acc[mt][1][r]);
                float gt = tanhf_(acc[mt][2][r]);
                float og = sigmoidf_(acc[mt][3][r]);
                float c = fmaf(fg, cst[mt][r], ig * gt);
                cst[mt][r] = c;
                float hv = og * tanhf_(c);
                int seq = mt * 16 + q * 4 + r;
                if (t == 11) {
                    hob[seq * 64 + hid] = hv;
                } else {
                    int elem = seq * 64 + (hid ^ ((seq & 7) << 3));
                    hwH[elem] = bf16_hi_trunc(hv);
                    hwH[4096 + elem] = bf16_rne(hv - trunc_bf16_f32(hv));
                }
            }
        }
        __syncthreads();
    }
}

// T1[slot][o][b][mm][c][l] = sum_n G[br][o][n][mm] * Xin[br,b][n][c][l]
__global__ __launch_bounds__(256) void k_t1(
    const float* __restrict__ Xin, const float* __restrict__ G,
    float* __restrict__ T1, int br0)
{
    const int br = br0 + blockIdx.z;
    const int slot = blockIdx.z;
    const int o = blockIdx.y >> 3, b = blockIdx.y & 7;
    const int cl = blockIdx.x * 256 + threadIdx.x;            // c*64+l
    const float* xp = Xin + (size_t)(br * 8 + b) * 262144 + cl;
    const float* gp = G + (size_t)((br * 3 + o) * 64) * 64;   // [n][mm]
    float acc[64];
#pragma unroll
    for (int mm = 0; mm < 64; ++mm) acc[mm] = 0.f;
#pragma unroll 4
    for (int n = 0; n < 64; ++n) {
        float xv = xp[(size_t)n * 4096];
        const float* gr = gp + n * 64;
#pragma unroll
        for (int mm = 0; mm < 64; ++mm) acc[mm] = fmaf(xv, gr[mm], acc[mm]);
    }
    float* tp = T1 + (size_t)slot * 6291456 +
                (size_t)((o * 8 + b) * 64) * 4096 + cl;
#pragma unroll
    for (int mm = 0; mm < 64; ++mm) tp[(size_t)mm * 4096] = acc[mm];
}

// Per (br, b, mm): out[e][h] = sum_{o,d,l} W[(o*3+d)*64+l][h] * Z_od[e][l],
//   Z_od[e][l] = sum_c G[br][d][c][e] * T1[o][b][mm][c][l]
__global__ __launch_bounds__(256) void k_t2fc(
    const float* __restrict__ T1, const float* __restrict__ G,
    const float* __restrict__ W, const float* __restrict__ bias,
    float* __restrict__ Y, int br0)
{
    __shared__ float t1s[3 * 64 * 64];
    __shared__ float zl[64 * 65];
    const int br = br0 + blockIdx.z;
    const int slot = blockIdx.z;
    const int mm = blockIdx.x, b = blockIdx.y;
    const int lane = threadIdx.x & 63;
    const int q = __builtin_amdgcn_readfirstlane(threadIdx.x >> 6);  // 0..3

    for (int i = threadIdx.x; i < 3 * 4096; i += 256)
        t1s[i] = T1[(size_t)slot * 6291456 +
                    (size_t)(((i >> 12) * 8 + b) * 64 + mm) * 4096 + (i & 4095)];
    __syncthreads();

    float out[16];
#pragma unroll
    for (int j = 0; j < 16; ++j) out[j] = 0.f;

    const float* gb = G + (size_t)(br * 3) * 4096;
    const float* wb = W + (size_t)br * 576 * 64;

    for (int o = 0; o < 3; ++o) {
        for (int d = 0; d < 3; ++d) {
            float z[16];
#pragma unroll
            for (int j = 0; j < 16; ++j) z[j] = 0.f;
            const float* t1c = t1s + o * 4096 + lane;
            const float* gd = gb + d * 4096 + q * 16;
#pragma unroll 2
            for (int cc = 0; cc < 64; ++cc) {
                float tv = t1c[cc * 64];
                const float* gr = gd + cc * 64;
#pragma unroll
                for (int j = 0; j < 16; ++j) z[j] = fmaf(tv, gr[j], z[j]);
            }
#pragma unroll
            for (int j = 0; j < 16; ++j) zl[(q * 16 + j) * 65 + lane] = z[j];
            __syncthreads();
            const float* wr = wb + (size_t)((o * 3 + d) * 64) * 64 + q * 16;
            const float* zr = zl + lane * 65;
#pragma unroll 2
            for (int l = 0; l < 64; ++l) {
                float zv = zr[l];
                const float* w4 = wr + l * 64;
#pragma unroll
                for (int j = 0; j < 16; ++j) out[j] = fmaf(zv, w4[j], out[j]);
            }
            __syncthreads();
        }
    }
#pragma unroll
    for (int j = 0; j < 16; ++j) zl[lane * 65 + q * 16 + j] = out[j];
    __syncthreads();
    const float bv = bias[br * 64 + lane];
    float* yp = Y + (size_t)(br * 8 + b) * 262144 + (size_t)mm * 4096 + lane;
#pragma unroll
    for (int j = 0; j < 16; ++j) {
        int e = q * 16 + j;
        yp[(size_t)e * 64] = zl[e * 65 + lane] + bv;
    }
}

__global__ __launch_bounds__(256) void k_fc(
    const float* __restrict__ Y2, const float* __restrict__ fcW,
    const float* __restrict__ fcb, float* __restrict__ out)
{
    int idx = blockIdx.x * 256 + threadIdx.x;  // b*4096 + n*64 + d
    int b = idx >> 12, nd = idx & 4095;
    float r = 0.f;
#pragma unroll
    for (int br = 0; br < 2; ++br) {
        const float4* yp =
            (const float4*)(Y2 + (size_t)(br * 8 + b) * 262144 + (size_t)nd * 64);
        float acc = 0.f;
#pragma unroll
        for (int v = 0; v < 16; ++v) {
            float4 y4 = yp[v];
            const float* fw = fcW + br * 64 + v * 4;
            acc += y4.x * fw[0] + y4.y * fw[1] + y4.z * fw[2] + y4.w * fw[3];
        }
        acc += fcb[br];
        r += fmaxf(acc, 0.f);
    }
    out[idx] = 0.5f * r;
}

extern "C" void kernel_launch(void* const* d_in, const int* in_sizes, int n_in,
                              void* d_out, int out_size, void* d_ws, size_t ws_size,
                              hipStream_t stream)
{
    const float* x   = (const float*)d_in[0];
    const float* G   = (const float*)d_in[1];
    const float* wih = (const float*)d_in[2];
    const float* whh = (const float*)d_in[3];
    const float* bih = (const float*)d_in[4];
    const float* bhh = (const float*)d_in[5];
    const float* W0  = (const float*)d_in[6];
    const float* b0  = (const float*)d_in[7];
    const float* W1  = (const float*)d_in[8];
    const float* b1  = (const float*)d_in[9];
    const float* fcW = (const float*)d_in[10];
    const float* fcb = (const float*)d_in[11];
    float* out = (float*)d_out;

    float* ws = (float*)d_ws;
    float* X0 = ws;                 // 4,194,304 floats (LSTM h / layer2 out)
    float* Y1 = ws + 4194304;       // 4,194,304 floats (layer1 out)
    float* T1 = ws + 8388608;       // 6.29M (narrow) or 12.58M (wide) floats
    const bool wide = ws_size >= (size_t)(8388608 + 2 * 6291456) * 4;

    k_lstm<<<dim3(512, 2), 256, 0, stream>>>(x, whh, wih, bih, bhh, X0);

    if (wide) {
        k_t1<<<dim3(16, 24, 2), 256, 0, stream>>>(X0, G, T1, 0);
        k_t2fc<<<dim3(64, 8, 2), 256, 0, stream>>>(T1, G, W0, b0, Y1, 0);
        k_t1<<<dim3(16, 24, 2), 256, 0, stream>>>(Y1, G, T1, 0);
        k_t2fc<<<dim3(64, 8, 2), 256, 0, stream>>>(T1, G, W1, b1, X0, 0);
    } else {
        for (int br = 0; br < 2; ++br) {
            k_t1<<<dim3(16, 24, 1), 256, 0, stream>>>(X0, G, T1, br);
            k_t2fc<<<dim3(64, 8, 1), 256, 0, stream>>>(T1, G, W0, b0, Y1, br);
        }
        for (int br = 0; br < 2; ++br) {
            k_t1<<<dim3(16, 24, 1), 256, 0, stream>>>(Y1, G, T1, br);
            k_t2fc<<<dim3(64, 8, 1), 256, 0, stream>>>(T1, G, W1, b1, X0, br);
        }
    }
    k_fc<<<128, 256, 0, stream>>>(X0, fcW, fcb, out);
}

// Round 3
// 394.191 us; speedup vs baseline: 2.7030x; 1.8997x over previous
//
#include <hip/hip_runtime.h>
#include <hip/hip_bf16.h>

// M=2 branches, K=3 diffusion, N=64, I=1, H=64, B=8, T=12

typedef __attribute__((ext_vector_type(8))) short short8;   // 8 bf16 (4 VGPRs)
typedef __attribute__((ext_vector_type(4))) float f32x4;    // 4 fp32

__device__ __forceinline__ short bf16_hi_trunc(float f) {
    union { float f; unsigned u; } v; v.f = f;
    return (short)(v.u >> 16);
}
__device__ __forceinline__ float trunc_bf16_f32(float f) {
    union { float f; unsigned u; } v; v.f = f;
    v.u &= 0xFFFF0000u;
    return v.f;
}
__device__ __forceinline__ short bf16_rne(float f) {
    union { float f; unsigned u; } v; v.f = f;
    unsigned r = ((v.u >> 16) & 1u) + 0x7FFFu;
    return (short)((v.u + r) >> 16);
}
__device__ __forceinline__ float from_bf16(unsigned short s) {
    union { unsigned u; float f; } v; v.u = ((unsigned)s) << 16;
    return v.f;
}
__device__ __forceinline__ float sigmoidf_(float x) {
    return 1.f / (1.f + __expf(-x));
}
__device__ __forceinline__ float tanhf_(float x) {
    float e = __expf(-2.f * x);
    return fmaf(2.f, 1.f / (1.f + e), -1.f);
}

// ---------------- prep: pack W and G^T into MFMA B/A fragment order --------
// Wf[layer][br][d][ht][kk][lane][8]: B1[k=(o,l)][h], k=kk*32+(lane>>4)*8+j,
//   o=k>>6, l=k&63, h=ht*16+(lane&15).   147456 elems per plane.
// Gf[br][et][kk][lane][8]: A2[e][k=(d,c)], d=k>>6, c=k&63, e=et*16+(lane&15).
//   24576 elems per plane.
__global__ __launch_bounds__(256) void k_prep(
    const float* __restrict__ G, const float* __restrict__ W0,
    const float* __restrict__ W1,
    short* __restrict__ Wfhi, short* __restrict__ Wflo,
    short* __restrict__ Gfhi, short* __restrict__ Gflo)
{
    int idx = blockIdx.x * 256 + threadIdx.x;
    float v; short *dh, *dl; int didx;
    if (idx < 147456) {
        int j = idx & 7, lane = (idx >> 3) & 63, kk = (idx >> 9) % 6;
        int t2 = idx / 3072;
        int ht = t2 & 3; t2 >>= 2;
        int d = t2 % 3; t2 /= 3;
        int br = t2 & 1, layer = t2 >> 1;
        int k = kk * 32 + ((lane >> 4) << 3) + j;
        int o = k >> 6, l = k & 63, h = ht * 16 + (lane & 15);
        const float* Wp = layer ? W1 : W0;
        v = Wp[((size_t)br * 576 + (o * 3 + d) * 64 + l) * 64 + h];
        dh = Wfhi; dl = Wflo; didx = idx;
    } else {
        int i2 = idx - 147456;
        int j = i2 & 7, lane = (i2 >> 3) & 63, kk = (i2 >> 9) % 6;
        int t2 = i2 / 3072;
        int et = t2 & 3, br = t2 >> 2;
        int k = kk * 32 + ((lane >> 4) << 3) + j;
        int d = k >> 6, c = k & 63, e = et * 16 + (lane & 15);
        v = G[(((size_t)br * 3 + d) * 64 + c) * 64 + e];
        dh = Gfhi; dl = Gflo; didx = i2;
        (void)j;
    }
    dh[didx] = bf16_hi_trunc(v);
    dl[didx] = bf16_rne(v - trunc_bf16_f32(v));
}

// ---------------- LSTM (bf16x3 MFMA, unchanged math; bf16 hi/lo output) ----
__global__ __launch_bounds__(256, 2) void k_lstm(
    const float* __restrict__ x, const float* __restrict__ whh,
    const float* __restrict__ wih, const float* __restrict__ bih,
    const float* __restrict__ bhh, short* __restrict__ Xhi,
    short* __restrict__ Xlo)
{
    __shared__ short hbuf[2][2][64][64];  // [dbuf][hi/lo][seq][hid ^ swz]
    const int tid = threadIdx.x;
    const int lane = tid & 63;
    const int w = __builtin_amdgcn_readfirstlane(tid >> 6);
    const int q = lane >> 4;
    const int r16 = lane & 15;
    const int br = blockIdx.y;
    const int b = blockIdx.x >> 6, o = blockIdx.x & 63;

    short8 Bhi[2][4], Blo[2][4];
    float wihv[4], biasv[4];
#pragma unroll
    for (int gg = 0; gg < 4; ++gg) {
        const int gate = gg * 64 + w * 16 + r16;
        wihv[gg] = wih[br * 256 + gate];
        biasv[gg] = bih[br * 256 + gate] + bhh[br * 256 + gate];
#pragma unroll
        for (int kt = 0; kt < 2; ++kt) {
            const float* wp = whh + ((size_t)br * 256 + gate) * 64 + kt * 32 + q * 8;
            float4 f0 = *(const float4*)wp;
            float4 f1 = *(const float4*)(wp + 4);
            float fv[8] = {f0.x, f0.y, f0.z, f0.w, f1.x, f1.y, f1.z, f1.w};
            short8 hi8, lo8;
#pragma unroll
            for (int j = 0; j < 8; ++j) {
                hi8[j] = bf16_hi_trunc(fv[j]);
                lo8[j] = bf16_rne(fv[j] - trunc_bf16_f32(fv[j]));
            }
            Bhi[kt][gg] = hi8;
            Blo[kt][gg] = lo8;
        }
    }

    float cst[4][4];
#pragma unroll
    for (int mt = 0; mt < 4; ++mt)
#pragma unroll
        for (int r = 0; r < 4; ++r) cst[mt][r] = 0.f;

    const float* xb = x + (((size_t)b * 12) * 64 + o) * 64;
    const size_t hob = ((size_t)(br * 8 + b) * 64 + o) * 4096;

    for (int t = 0; t < 12; ++t) {
        f32x4 acc[4][4];   // [mt][gg]
        const float* xrow = xb + (size_t)t * 4096;
#pragma unroll
        for (int mt = 0; mt < 4; ++mt) {
#pragma unroll
            for (int r = 0; r < 4; ++r) {
                float xv = xrow[mt * 16 + q * 4 + r];
#pragma unroll
                for (int gg = 0; gg < 4; ++gg)
                    acc[mt][gg][r] = fmaf(xv, wihv[gg], biasv[gg]);
            }
        }
        if (t > 0) {
            const short* hb = &hbuf[t & 1][0][0][0];
#pragma unroll
            for (int kt = 0; kt < 2; ++kt) {
                short8 Ahi[4], Alo[4];
#pragma unroll
                for (int mt = 0; mt < 4; ++mt) {
                    int elem = (mt * 16 + r16) * 64 +
                               ((kt * 32 + q * 8) ^ ((r16 & 7) << 3));
                    Ahi[mt] = *(const short8*)(hb + elem);
                    Alo[mt] = *(const short8*)(hb + 4096 + elem);
                }
#pragma unroll
                for (int mt = 0; mt < 4; ++mt)
#pragma unroll
                    for (int gg = 0; gg < 4; ++gg) {
                        acc[mt][gg] = __builtin_amdgcn_mfma_f32_16x16x32_bf16(
                            Ahi[mt], Bhi[kt][gg], acc[mt][gg], 0, 0, 0);
                        acc[mt][gg] = __builtin_amdgcn_mfma_f32_16x16x32_bf16(
                            Ahi[mt], Blo[kt][gg], acc[mt][gg], 0, 0, 0);
                        acc[mt][gg] = __builtin_amdgcn_mfma_f32_16x16x32_bf16(
                            Alo[mt], Bhi[kt][gg], acc[mt][gg], 0, 0, 0);
                    }
            }
        }
        short* hwH = &hbuf[(t + 1) & 1][0][0][0];
        const int hid = w * 16 + r16;
#pragma unroll
        for (int mt = 0; mt < 4; ++mt) {
#pragma unroll
            for (int r = 0; r < 4; ++r) {
                float ig = sigmoidf_(acc[mt][0][r]);
                float fg = sigmoidf_(acc[mt][1][r]);
                float gt = tanhf_(acc[mt][2][r]);
                float og = sigmoidf_(acc[mt][3][r]);
                float c = fmaf(fg, cst[mt][r], ig * gt);
                cst[mt][r] = c;
                float hv = og * tanhf_(c);
                int seq = mt * 16 + q * 4 + r;
                if (t == 11) {
                    Xhi[hob + seq * 64 + hid] = bf16_hi_trunc(hv);
                    Xlo[hob + seq * 64 + hid] = bf16_rne(hv - trunc_bf16_f32(hv));
                } else {
                    int elem = seq * 64 + (hid ^ ((seq & 7) << 3));
                    hwH[elem] = bf16_hi_trunc(hv);
                    hwH[4096 + elem] = bf16_rne(hv - trunc_bf16_f32(hv));
                }
            }
        }
        __syncthreads();
    }
}

// ---------------- T1 (VALU fp32, hi/lo bf16 I/O) ---------------------------
// T1[br][o][b][m][cl] = sum_n G[br][o][n][m] * X[br][b][n][cl]
__global__ __launch_bounds__(256) void k_t1(
    const short* __restrict__ Xhi, const short* __restrict__ Xlo,
    const float* __restrict__ G,
    short* __restrict__ T1hi, short* __restrict__ T1lo)
{
    const int br = blockIdx.z;
    const int o = blockIdx.y >> 3, b = blockIdx.y & 7;
    const int cl = blockIdx.x * 256 + threadIdx.x;
    const unsigned short* xh = (const unsigned short*)Xhi;
    const unsigned short* xl = (const unsigned short*)Xlo;
    const size_t xb = ((size_t)(br * 8 + b) * 64) * 4096 + cl;
    const float* gp = G + ((size_t)(br * 3 + o) * 64) * 64;
    float acc[64];
#pragma unroll
    for (int mm = 0; mm < 64; ++mm) acc[mm] = 0.f;
#pragma unroll 4
    for (int n = 0; n < 64; ++n) {
        float xv = from_bf16(xh[xb + (size_t)n * 4096]) +
                   from_bf16(xl[xb + (size_t)n * 4096]);
        const float* gr = gp + n * 64;
#pragma unroll
        for (int mm = 0; mm < 64; ++mm) acc[mm] = fmaf(xv, gr[mm], acc[mm]);
    }
    const size_t tb = (((size_t)(br * 3 + o) * 8 + b) * 64) * 4096 + cl;
#pragma unroll
    for (int mm = 0; mm < 64; ++mm) {
        float f = acc[mm];
        T1hi[tb + (size_t)mm * 4096] = bf16_hi_trunc(f);
        T1lo[tb + (size_t)mm * 4096] = bf16_rne(f - trunc_bf16_f32(f));
    }
}

// ---------------- T2 + FC (MFMA) -------------------------------------------
// Per (br,b,m): U[d][c][h] = sum_{o,l} T1[o][c][l] W[(o,d)l][h]   (phase 1)
//              out[e][h]  = bias[h] + sum_{d,c} G[d][c][e] U[d][c][h] (ph 2)
// last==0: write out as Y hi/lo planes;  last==1: fuse fc+relu -> yws.
__global__ __launch_bounds__(256) void k_t2fc(
    const short* __restrict__ T1hi, const short* __restrict__ T1lo,
    const short* __restrict__ Wfhi, const short* __restrict__ Wflo,
    const short* __restrict__ Gfhi, const short* __restrict__ Gflo,
    const float* __restrict__ bias, const float* __restrict__ fcW,
    const float* __restrict__ fcb,
    short* __restrict__ Yhi, short* __restrict__ Ylo,
    float* __restrict__ yws, int last)
{
    __shared__ short ldsU[2][3][64][72];   // [plane][d][h][c] (+pad)
    short* u0 = &ldsU[0][0][0][0];
    short* u1 = &ldsU[1][0][0][0];
    const int tid = threadIdx.x, lane = tid & 63;
    const int r16 = lane & 15, q = lane >> 4;
    const int w = __builtin_amdgcn_readfirstlane(tid >> 6);
    const int m = blockIdx.x, b = blockIdx.y, br = blockIdx.z;

    // ---- phase 1: U = T1 @ W (wave w owns c-tile w)
    f32x4 acc1[3][4];
#pragma unroll
    for (int d = 0; d < 3; ++d)
#pragma unroll
        for (int ht = 0; ht < 4; ++ht)
#pragma unroll
            for (int r = 0; r < 4; ++r) acc1[d][ht][r] = 0.f;

    const size_t t1b = (((size_t)br * 3 * 8 + b) * 64 + m) * 4096;
#pragma unroll
    for (int kk = 0; kk < 6; ++kk) {
        const int o = kk >> 1;
        const size_t aoff = t1b + (size_t)o * (8 * 64 * 4096) +
                            (w * 16 + r16) * 64 + (kk & 1) * 32 + q * 8;
        short8 Ah = *(const short8*)(T1hi + aoff);
        short8 Al = *(const short8*)(T1lo + aoff);
#pragma unroll
        for (int d = 0; d < 3; ++d) {
#pragma unroll
            for (int ht = 0; ht < 4; ++ht) {
                const int widx = ((((br * 3 + d) * 4 + ht) * 6 + kk) << 9) + lane * 8;
                short8 Bh = *(const short8*)(Wfhi + widx);
                short8 Bl = *(const short8*)(Wflo + widx);
                acc1[d][ht] = __builtin_amdgcn_mfma_f32_16x16x32_bf16(
                    Ah, Bh, acc1[d][ht], 0, 0, 0);
                acc1[d][ht] = __builtin_amdgcn_mfma_f32_16x16x32_bf16(
                    Ah, Bl, acc1[d][ht], 0, 0, 0);
                acc1[d][ht] = __builtin_amdgcn_mfma_f32_16x16x32_bf16(
                    Al, Bh, acc1[d][ht], 0, 0, 0);
            }
        }
    }
    // write U to LDS transposed: ldsU[d][h][c]
#pragma unroll
    for (int d = 0; d < 3; ++d)
#pragma unroll
        for (int ht = 0; ht < 4; ++ht)
#pragma unroll
            for (int r = 0; r < 4; ++r) {
                float f = acc1[d][ht][r];
                int c = w * 16 + q * 4 + r;
                int h = ht * 16 + r16;
                int ui = (d * 64 + h) * 72 + c;
                u0[ui] = bf16_hi_trunc(f);
                u1[ui] = bf16_rne(f - trunc_bf16_f32(f));
            }
    __syncthreads();

    // ---- phase 2: out = G^T @ U + bias (wave w owns e-tile w)
    f32x4 acc2[4];
#pragma unroll
    for (int ht = 0; ht < 4; ++ht) {
        float bb = bias[br * 64 + ht * 16 + r16];
#pragma unroll
        for (int r = 0; r < 4; ++r) acc2[ht][r] = bb;
    }
#pragma unroll
    for (int kk = 0; kk < 6; ++kk) {
        const int gi = (((br * 4 + w) * 6 + kk) << 9) + lane * 8;
        short8 A2h = *(const short8*)(Gfhi + gi);
        short8 A2l = *(const short8*)(Gflo + gi);
        const int d = kk >> 1, cb = (kk & 1) * 32 + q * 8;
#pragma unroll
        for (int ht = 0; ht < 4; ++ht) {
            const int bi = (d * 64 + ht * 16 + r16) * 72 + cb;
            short8 B2h = *(const short8*)(u0 + bi);
            short8 B2l = *(const short8*)(u1 + bi);
            acc2[ht] = __builtin_amdgcn_mfma_f32_16x16x32_bf16(
                A2h, B2h, acc2[ht], 0, 0, 0);
            acc2[ht] = __builtin_amdgcn_mfma_f32_16x16x32_bf16(
                A2h, B2l, acc2[ht], 0, 0, 0);
            acc2[ht] = __builtin_amdgcn_mfma_f32_16x16x32_bf16(
                A2l, B2h, acc2[ht], 0, 0, 0);
        }
    }

    if (!last) {
        __syncthreads();
        float* ldsO = (float*)u0;   // 16 KB, fits in plane 0
#pragma unroll
        for (int ht = 0; ht < 4; ++ht)
#pragma unroll
            for (int r = 0; r < 4; ++r)
                ldsO[(w * 16 + q * 4 + r) * 64 + ht * 16 + r16] = acc2[ht][r];
        __syncthreads();
        const size_t yb = ((size_t)(br * 8 + b) * 64 + m) * 4096;
        const int i0 = tid * 16;
#pragma unroll
        for (int half = 0; half < 2; ++half) {
            short8 h8, l8;
#pragma unroll
            for (int ii = 0; ii < 8; ++ii) {
                float f = ldsO[i0 + half * 8 + ii];
                h8[ii] = bf16_hi_trunc(f);
                l8[ii] = bf16_rne(f - trunc_bf16_f32(f));
            }
            *(short8*)(Yhi + yb + i0 + half * 8) = h8;
            *(short8*)(Ylo + yb + i0 + half * 8) = l8;
        }
    } else {
        float p[4];
#pragma unroll
        for (int r = 0; r < 4; ++r) {
            p[r] = 0.f;
#pragma unroll
            for (int ht = 0; ht < 4; ++ht)
                p[r] += acc2[ht][r] * fcW[br * 64 + ht * 16 + r16];
        }
#pragma unroll
        for (int off = 1; off < 16; off <<= 1)
#pragma unroll
            for (int r = 0; r < 4; ++r) p[r] += __shfl_xor(p[r], off);
        if (r16 == 0) {
            float fb = fcb[br];
#pragma unroll
            for (int r = 0; r < 4; ++r) {
                int e = w * 16 + q * 4 + r;
                yws[(size_t)br * 32768 + (size_t)b * 4096 + m * 64 + e] =
                    fmaxf(p[r] + fb, 0.f);
            }
        }
    }
}

__global__ __launch_bounds__(256) void k_mean(
    const float* __restrict__ yws, float* __restrict__ out)
{
    int idx = blockIdx.x * 256 + threadIdx.x;
    out[idx] = 0.5f * (yws[idx] + yws[32768 + idx]);
}

extern "C" void kernel_launch(void* const* d_in, const int* in_sizes, int n_in,
                              void* d_out, int out_size, void* d_ws, size_t ws_size,
                              hipStream_t stream)
{
    const float* x   = (const float*)d_in[0];
    const float* G   = (const float*)d_in[1];
    const float* wih = (const float*)d_in[2];
    const float* whh = (const float*)d_in[3];
    const float* bih = (const float*)d_in[4];
    const float* bhh = (const float*)d_in[5];
    const float* W0  = (const float*)d_in[6];
    const float* b0  = (const float*)d_in[7];
    const float* W1  = (const float*)d_in[8];
    const float* b1  = (const float*)d_in[9];
    const float* fcW = (const float*)d_in[10];
    const float* fcb = (const float*)d_in[11];
    float* out = (float*)d_out;

    // ws layout (shorts unless noted). Total ~68.1 MB.
    short* Xhi  = (short*)d_ws;            // 4,194,304
    short* Xlo  = Xhi + 4194304;
    short* T1hi = Xlo + 4194304;           // 12,582,912
    short* T1lo = T1hi + 12582912;
    float* yws  = (float*)(T1lo + 12582912);  // 65,536 f32
    short* Wfhi = (short*)(yws + 65536);   // 147,456
    short* Wflo = Wfhi + 147456;
    short* Gfhi = Wflo + 147456;           // 24,576
    short* Gflo = Gfhi + 24576;
    // Y1 reuses X planes (X dead after layer-1 k_t1)
    short* Y1hi = Xhi;
    short* Y1lo = Xlo;

    k_prep<<<672, 256, 0, stream>>>(G, W0, W1, Wfhi, Wflo, Gfhi, Gflo);
    k_lstm<<<dim3(512, 2), 256, 0, stream>>>(x, whh, wih, bih, bhh, Xhi, Xlo);

    // layer 1
    k_t1<<<dim3(16, 24, 2), 256, 0, stream>>>(Xhi, Xlo, G, T1hi, T1lo);
    k_t2fc<<<dim3(64, 8, 2), 256, 0, stream>>>(T1hi, T1lo, Wfhi, Wflo,
                                               Gfhi, Gflo, b0, fcW, fcb,
                                               Y1hi, Y1lo, yws, 0);
    // layer 2
    k_t1<<<dim3(16, 24, 2), 256, 0, stream>>>(Y1hi, Y1lo, G, T1hi, T1lo);
    k_t2fc<<<dim3(64, 8, 2), 256, 0, stream>>>(T1hi, T1lo,
                                               Wfhi + 73728, Wflo + 73728,
                                               Gfhi, Gflo, b1, fcW, fcb,
                                               (short*)nullptr, (short*)nullptr,
                                               yws, 1);
    k_mean<<<128, 256, 0, stream>>>(yws, out);
}